// Round 1
// baseline (3615.273 us; speedup 1.0000x reference)
//
#include <hip/hip_runtime.h>
#include <cmath>

// Problem constants
static constexpr int NB   = 128;   // batch
static constexpr int NT   = 512;   // time
static constexpr int ND   = 128;   // embed dim
static constexpr int NH   = 128;   // hidden per direction
static constexpr int NG4  = 512;   // 4*H
static constexpr int NKT  = 32;    // num tags
static constexpr int CHUNK = 128;  // timesteps per chunk
static constexpr int NCH  = NT / CHUNK;

__device__ __forceinline__ float sigf(float x) { return 1.0f / (1.0f + expf(-x)); }

// ---------------------------------------------------------------------------
// Projection kernel: zin[d][b][s][j] = bias[d][j] + sum_k Wih[d][j][k] * X(b, t(d,c,s), k)
// grid = 512 blocks: bid = d*256 + b*2 + jhalf ; block = 1024 threads
// thread (q in 0..3, jl in 0..255): holds DIN/4 weights of row j = jhalf*256+jl
// ---------------------------------------------------------------------------
template <int DIN>
__global__ __launch_bounds__(1024) void proj_kernel(
    const float* __restrict__ Wih,    // [2][512][DIN]
    const float* __restrict__ bias,   // [2][512]
    const float* __restrict__ xsrc,   // emb [V][128] (layer0) or h1 [B][T][256] (layer1)
    const int*   __restrict__ inputs, // [B][T] (layer0 only)
    float*       __restrict__ zin,    // [2][B][CHUNK][512]
    int c)
{
    constexpr int WQ = DIN / 4;  // weights per thread (32 or 64)
    __shared__ __align__(16) float u_lds[DIN];
    __shared__ float p_lds[1024];

    const int bid = blockIdx.x;
    const int d   = bid >> 8;
    const int b   = (bid >> 1) & 127;
    const int jh  = bid & 1;
    const int tid = threadIdx.x;
    const int jl  = tid & 255;
    const int q   = tid >> 8;  // 0..3
    const int j   = jh * 256 + jl;

    // Load this thread's weight slice into registers.
    float w[WQ];
    const float* wrow = Wih + ((size_t)(d * NG4 + j)) * DIN + q * WQ;
#pragma unroll
    for (int kk = 0; kk < WQ; kk += 4) {
        float4 t4 = *(const float4*)(wrow + kk);
        w[kk] = t4.x; w[kk + 1] = t4.y; w[kk + 2] = t4.z; w[kk + 3] = t4.w;
    }
    const float bj = bias[d * NG4 + j];

    for (int s = 0; s < CHUNK; ++s) {
        const int ttl = c * CHUNK + s;
        const int t   = d ? (NT - 1 - ttl) : ttl;
        // stage input row into LDS
        const float* row;
        if constexpr (DIN == 128) {
            const int idx = inputs[b * NT + t];
            row = xsrc + (size_t)idx * ND;
        } else {
            row = xsrc + ((size_t)(b * NT + t)) * 256;
        }
        if (tid < DIN / 4) {
            ((float4*)u_lds)[tid] = ((const float4*)row)[tid];
        }
        __syncthreads();

        float acc = 0.0f;
        const float* up = u_lds + q * WQ;
#pragma unroll
        for (int kk = 0; kk < WQ; kk += 4) {
            float4 uv = *(const float4*)(up + kk);
            acc += w[kk] * uv.x + w[kk + 1] * uv.y + w[kk + 2] * uv.z + w[kk + 3] * uv.w;
        }
        p_lds[tid] = acc;
        __syncthreads();

        if (tid < 256) {
            float z = bj + p_lds[tid] + p_lds[256 + tid] + p_lds[512 + tid] + p_lds[768 + tid];
            zin[((size_t)(d * NB + b) * CHUNK + s) * NG4 + j] = z;
        }
        // No extra sync needed: next iter's u_lds staging is fenced by the next
        // __syncthreads() before any read; p_lds rewrite happens after it too.
        __syncthreads();
    }
}

// ---------------------------------------------------------------------------
// Recurrent kernel: one block per (d,b). Whh rows in VGPRs, h broadcast via LDS.
// thread (q in 0..1, j in 0..511): 64 weights of row j.
// ---------------------------------------------------------------------------
__global__ __launch_bounds__(1024) void lstm_rec_kernel(
    const float* __restrict__ Whh,     // [2][512][128]
    const float* __restrict__ zin,     // [2][B][CHUNK][512]
    float*       __restrict__ hout,    // [B][T][256]; we write slice [d*128 .. d*128+128)
    float*       __restrict__ state_h, // [2][B][128]
    float*       __restrict__ state_c, // [2][B][128]
    int c)
{
    __shared__ __align__(16) float h_lds[128];
    __shared__ float p_lds[1024];

    const int bid = blockIdx.x;  // d*128 + b
    const int d = bid >> 7, b = bid & 127;
    const int tid = threadIdx.x;
    const int j = tid & 511, q = tid >> 9;

    float w[64];
    const float* wrow = Whh + ((size_t)(d * NG4 + j)) * NH + q * 64;
#pragma unroll
    for (int kk = 0; kk < 64; kk += 4) {
        float4 t4 = *(const float4*)(wrow + kk);
        w[kk] = t4.x; w[kk + 1] = t4.y; w[kk + 2] = t4.z; w[kk + 3] = t4.w;
    }

    float c_reg = 0.0f;
    if (tid < 128) {
        float h0 = 0.0f;
        if (c != 0) {
            h0    = state_h[(d * NB + b) * NH + tid];
            c_reg = state_c[(d * NB + b) * NH + tid];
        }
        h_lds[tid] = h0;
    }
    __syncthreads();

    const float* zb = zin + ((size_t)(d * NB + b)) * CHUNK * NG4;

    for (int s = 0; s < CHUNK; ++s) {
        // gate threads prefetch this step's zin early (latency hides under FMA)
        float z0 = 0.f, z1 = 0.f, z2 = 0.f, z3 = 0.f;
        if (tid < 128) {
            const float* zr = zb + (size_t)s * NG4;
            z0 = zr[tid]; z1 = zr[128 + tid]; z2 = zr[256 + tid]; z3 = zr[384 + tid];
        }
        float acc = 0.0f;
        const float* hp = h_lds + q * 64;
#pragma unroll
        for (int kk = 0; kk < 64; kk += 4) {
            float4 hv = *(const float4*)(hp + kk);
            acc += w[kk] * hv.x + w[kk + 1] * hv.y + w[kk + 2] * hv.z + w[kk + 3] * hv.w;
        }
        p_lds[tid] = acc;
        __syncthreads();

        if (tid < 128) {
            const float zi = z0 + p_lds[tid]       + p_lds[512 + tid];
            const float zf = z1 + p_lds[128 + tid] + p_lds[640 + tid];
            const float zg = z2 + p_lds[256 + tid] + p_lds[768 + tid];
            const float zo = z3 + p_lds[384 + tid] + p_lds[896 + tid];
            const float ig = sigf(zi), fg = sigf(zf), og = sigf(zo);
            c_reg = fg * c_reg + ig * tanhf(zg);
            const float hn = og * tanhf(c_reg);
            const int ttl = c * CHUNK + s;
            const int t   = d ? (NT - 1 - ttl) : ttl;
            h_lds[tid] = hn;
            hout[((size_t)(b * NT + t)) * 256 + d * NH + tid] = hn;
        }
        __syncthreads();
    }

    if (tid < 128) {
        state_h[(d * NB + b) * NH + tid] = h_lds[tid];
        state_c[(d * NB + b) * NH + tid] = c_reg;
    }
}

// ---------------------------------------------------------------------------
// Emissions: em[b][t][k] = b_out[k] + sum_c h2[b][t][c] * W_out[k][c]
// 1024 blocks x 256 threads; each block does 64 rows (8 iters of 8 rows).
// W_out staged transposed [c][k] in LDS (conflict-free reads).
// ---------------------------------------------------------------------------
__global__ __launch_bounds__(256) void emis_kernel(
    const float* __restrict__ h2,    // [B][T][256]
    const float* __restrict__ Wout,  // [32][256]
    const float* __restrict__ bout,  // [32]
    float*       __restrict__ em)    // [B][T][32]
{
    __shared__ float wt[256 * 32];               // transposed [c][k]
    __shared__ __align__(16) float hrow[8][256];

    const int tid = threadIdx.x;
    const int k = tid & 31;
    const int rl = tid >> 5;  // 0..7

    for (int e = tid; e < 8192; e += 256) {
        const int kk = e >> 8, cc = e & 255;
        wt[cc * 32 + kk] = Wout[e];
    }
    const float bk = bout[k];
    __syncthreads();

    const size_t base = (size_t)blockIdx.x * 64;
    for (int rr = 0; rr < 8; ++rr) {
        const size_t r0 = base + rr * 8;
        for (int e = tid; e < 512; e += 256) {  // 2048 floats as float4
            ((float4*)&hrow[0][0])[e] = ((const float4*)(h2 + r0 * 256))[e];
        }
        __syncthreads();
        float acc = bk;
#pragma unroll 8
        for (int cc = 0; cc < 256; cc += 4) {
            float4 hv = *(const float4*)&hrow[rl][cc];
            acc += hv.x * wt[cc * 32 + k] + hv.y * wt[(cc + 1) * 32 + k] +
                   hv.z * wt[(cc + 2) * 32 + k] + hv.w * wt[(cc + 3) * 32 + k];
        }
        em[(r0 + rl) * NKT + k] = acc;
        __syncthreads();
    }
}

// ---------------------------------------------------------------------------
// Viterbi: one block (1 wave) per batch row. hist kept in LDS; backtrack in-LDS.
// Replicates np add order ((score+trans)+em) and first-index argmax ties.
// lane = j + 32*h ; half h reduces over i in [h*16, h*16+16)
// ---------------------------------------------------------------------------
__global__ __launch_bounds__(64) void viterbi_kernel(
    const float* __restrict__ em,      // [B][T][32]
    const float* __restrict__ start_t, // [32]
    const float* __restrict__ end_t,   // [32]
    const float* __restrict__ trans,   // [32][32]
    int*         __restrict__ out)     // [B][T]
{
    __shared__ float score[32];
    __shared__ float tr[1024];
    __shared__ float fsc[32];
    __shared__ unsigned char hist[(NT - 1) * 32];

    const int b = blockIdx.x;
    const int lane = threadIdx.x;
    const int j = lane & 31, h = lane >> 5;

    for (int e = lane; e < 1024; e += 64) tr[e] = trans[e];
    const float* emb_ = em + (size_t)b * NT * NKT;
    if (lane < 32) score[j] = start_t[j] + emb_[j];
    __syncthreads();

    float em_next = emb_[NKT + j];  // t = 1
    for (int t = 1; t < NT; ++t) {
        const float em_j = em_next;
        if (t + 1 < NT) em_next = emb_[(size_t)(t + 1) * NKT + j];
        float best = -1e30f;
        int bi = 0;
#pragma unroll
        for (int ii = 0; ii < 16; ++ii) {
            const int i = h * 16 + ii;
            const float v = (score[i] + tr[i * 32 + j]) + em_j;  // np add order
            if (v > best) { best = v; bi = i; }                  // strict >: first index wins
        }
        const float ob  = __shfl(best, lane ^ 32);
        const int   obi = __shfl(bi,   lane ^ 32);
        __syncthreads();
        if (h == 0) {
            float ns; int arg;
            if (ob > best) { ns = ob; arg = obi; }  // tie -> low half (smaller i)
            else           { ns = best; arg = bi; }
            score[j] = ns;
            hist[(t - 1) * 32 + j] = (unsigned char)arg;
        }
        __syncthreads();
    }

    if (lane < 32) fsc[j] = score[j] + end_t[j];
    __syncthreads();
    if (lane == 0) {
        float best = -1e30f; int bi = 0;
        for (int i = 0; i < 32; ++i) {
            const float v = fsc[i];
            if (v > best) { best = v; bi = i; }
        }
        int tag = bi;
        out[b * NT + (NT - 1)] = tag;
        for (int t = NT - 2; t >= 0; --t) {
            tag = hist[t * 32 + tag];
            out[b * NT + t] = tag;
        }
    }
}

// ---------------------------------------------------------------------------
extern "C" void kernel_launch(void* const* d_in, const int* in_sizes, int n_in,
                              void* d_out, int out_size, void* d_ws, size_t ws_size,
                              hipStream_t stream) {
    const int*   inputs  = (const int*)d_in[0];
    // d_in[1] = tags (unused by forward/decode)
    const float* emb     = (const float*)d_in[2];
    const float* w_ih_l0 = (const float*)d_in[3];
    const float* w_hh_l0 = (const float*)d_in[4];
    const float* b_l0    = (const float*)d_in[5];
    const float* w_ih_l1 = (const float*)d_in[6];
    const float* w_hh_l1 = (const float*)d_in[7];
    const float* b_l1    = (const float*)d_in[8];
    const float* W_out   = (const float*)d_in[9];
    const float* b_out   = (const float*)d_in[10];
    const float* start_t = (const float*)d_in[11];
    const float* end_t   = (const float*)d_in[12];
    const float* trans   = (const float*)d_in[13];
    int* out = (int*)d_out;

    float* ws  = (float*)d_ws;
    float* zin = ws;                                        // 2*B*CHUNK*512 = 16,777,216
    float* h1  = zin + (size_t)2 * NB * CHUNK * NG4;        // B*T*256       = 16,777,216
    float* h2  = h1 + (size_t)NB * NT * 256;                //               = 16,777,216
    float* sth = h2 + (size_t)NB * NT * 256;                // 2*B*128
    float* stc = sth + (size_t)2 * NB * NH;                 // 2*B*128
    float* em  = stc + (size_t)2 * NB * NH;                 // B*T*32        = 2,097,152

    // Layer 0: chunked input-projection + recurrence
    for (int c = 0; c < NCH; ++c) {
        proj_kernel<128><<<512, 1024, 0, stream>>>(w_ih_l0, b_l0, emb, inputs, zin, c);
        lstm_rec_kernel<<<256, 1024, 0, stream>>>(w_hh_l0, zin, h1, sth, stc, c);
    }
    // Layer 1
    for (int c = 0; c < NCH; ++c) {
        proj_kernel<256><<<512, 1024, 0, stream>>>(w_ih_l1, b_l1, h1, nullptr, zin, c);
        lstm_rec_kernel<<<256, 1024, 0, stream>>>(w_hh_l1, zin, h2, sth, stc, c);
    }
    // Emissions + Viterbi decode
    emis_kernel<<<(NB * NT) / 64, 256, 0, stream>>>(h2, W_out, b_out, em);
    viterbi_kernel<<<NB, 64, 0, stream>>>(em, start_t, end_t, trans, out);
}

// Round 2
// 2250.814 us; speedup vs baseline: 1.6062x; 1.6062x over previous
//
#include <hip/hip_runtime.h>
#include <cmath>

// Problem constants
static constexpr int NB   = 128;   // batch
static constexpr int NT   = 512;   // time
static constexpr int ND   = 128;   // embed dim
static constexpr int NH   = 128;   // hidden per direction
static constexpr int NG4  = 512;   // 4*H
static constexpr int NKT  = 32;    // num tags
static constexpr int CHUNK = 128;  // timesteps per chunk
static constexpr int NCH  = NT / CHUNK;

__device__ __forceinline__ float sigf(float x) { return 1.0f / (1.0f + expf(-x)); }

// ---------------------------------------------------------------------------
// Projection GEMM: zin[d][b][s][j] = bias[d][j] + sum_k Wih[d][j][k] * X(b,t(d,c,s),k)
// Fully parallel over (d, b, s, j). Block tile: 128 rows (s) x 256 cols (j),
// 256 threads, each thread 8 rows x 16 cols (4 col-groups of 4 for bank-free LDS).
// grid = 512: bid = d*256 + b*2 + ct
// ---------------------------------------------------------------------------
template <int DIN>
__global__ __launch_bounds__(256, 2) void proj_gemm(
    const float* __restrict__ Wih,    // [2][512][DIN]
    const float* __restrict__ bias,   // [2][512]
    const float* __restrict__ xsrc,   // emb [V][128] (l0) or h1 [B][T][256] (l1)
    const int*   __restrict__ inputs, // [B][T] (l0 only)
    float*       __restrict__ zin,    // [2][B][CHUNK][512]
    int c)
{
    constexpr int KT = DIN / 16;  // K-steps
    __shared__ __align__(16) float A[16][128];
    __shared__ __align__(16) float Bs[16][256];
    __shared__ const float* rowp[128];

    const int bid = blockIdx.x;
    const int d  = bid >> 8;
    const int b  = (bid >> 1) & 127;
    const int ct = bid & 1;
    const int tid = threadIdx.x;
    const int tx = tid & 15;   // col group: cols ct*256 + g*64 + tx*4, g=0..3
    const int ty = tid >> 4;   // row group: rows ty*8 .. ty*8+7
    const int rr = tid & 127;  // staging row
    const int kh = tid >> 7;   // staging k-half (0/1)

    // Per-row source pointers (gather for layer0).
    if (tid < 128) {
        const int s = tid;
        const int ttl = c * CHUNK + s;
        const int t = d ? (NT - 1 - ttl) : ttl;
        if constexpr (DIN == 128) {
            rowp[tid] = xsrc + (size_t)inputs[b * NT + t] * ND;
        } else {
            rowp[tid] = xsrc + ((size_t)(b * NT + t)) * 256;
        }
    }
    __syncthreads();

    const float* myrow = rowp[rr];                                  // A staging src
    const float* wrow  = Wih + ((size_t)(d * NG4 + ct * 256 + tid)) * DIN;  // B staging src

    float acc[8][16];
#pragma unroll
    for (int i = 0; i < 8; ++i)
#pragma unroll
        for (int n = 0; n < 16; ++n) acc[i][n] = 0.0f;

    // Prefetch kt=0 into registers.
    float4 pa0 = *(const float4*)(myrow + kh * 8);
    float4 pa1 = *(const float4*)(myrow + kh * 8 + 4);
    float4 pb0 = *(const float4*)(wrow + 0);
    float4 pb1 = *(const float4*)(wrow + 4);
    float4 pb2 = *(const float4*)(wrow + 8);
    float4 pb3 = *(const float4*)(wrow + 12);

    for (int kt = 0; kt < KT; ++kt) {
        __syncthreads();  // previous compute done; LDS safe to overwrite
        // Stage A: A[k][rr], k = kh*8 .. kh*8+7
        A[kh * 8 + 0][rr] = pa0.x; A[kh * 8 + 1][rr] = pa0.y;
        A[kh * 8 + 2][rr] = pa0.z; A[kh * 8 + 3][rr] = pa0.w;
        A[kh * 8 + 4][rr] = pa1.x; A[kh * 8 + 5][rr] = pa1.y;
        A[kh * 8 + 6][rr] = pa1.z; A[kh * 8 + 7][rr] = pa1.w;
        // Stage B transposed: Bs[k][tid], k = 0..15
        Bs[ 0][tid] = pb0.x; Bs[ 1][tid] = pb0.y; Bs[ 2][tid] = pb0.z; Bs[ 3][tid] = pb0.w;
        Bs[ 4][tid] = pb1.x; Bs[ 5][tid] = pb1.y; Bs[ 6][tid] = pb1.z; Bs[ 7][tid] = pb1.w;
        Bs[ 8][tid] = pb2.x; Bs[ 9][tid] = pb2.y; Bs[10][tid] = pb2.z; Bs[11][tid] = pb2.w;
        Bs[12][tid] = pb3.x; Bs[13][tid] = pb3.y; Bs[14][tid] = pb3.z; Bs[15][tid] = pb3.w;
        __syncthreads();

        // Prefetch next kt while computing this one.
        if (kt + 1 < KT) {
            const int k0 = (kt + 1) * 16;
            pa0 = *(const float4*)(myrow + k0 + kh * 8);
            pa1 = *(const float4*)(myrow + k0 + kh * 8 + 4);
            pb0 = *(const float4*)(wrow + k0 + 0);
            pb1 = *(const float4*)(wrow + k0 + 4);
            pb2 = *(const float4*)(wrow + k0 + 8);
            pb3 = *(const float4*)(wrow + k0 + 12);
        }

#pragma unroll 4
        for (int k = 0; k < 16; ++k) {
            float4 a0 = *(const float4*)&A[k][ty * 8];
            float4 a1 = *(const float4*)&A[k][ty * 8 + 4];
            float4 b0 = *(const float4*)&Bs[k][tx * 4];
            float4 b1 = *(const float4*)&Bs[k][64 + tx * 4];
            float4 b2 = *(const float4*)&Bs[k][128 + tx * 4];
            float4 b3 = *(const float4*)&Bs[k][192 + tx * 4];
            const float ar[8] = {a0.x, a0.y, a0.z, a0.w, a1.x, a1.y, a1.z, a1.w};
            const float br[16] = {b0.x, b0.y, b0.z, b0.w, b1.x, b1.y, b1.z, b1.w,
                                  b2.x, b2.y, b2.z, b2.w, b3.x, b3.y, b3.z, b3.w};
#pragma unroll
            for (int i = 0; i < 8; ++i)
#pragma unroll
                for (int n = 0; n < 16; ++n) acc[i][n] += ar[i] * br[n];
        }
    }

    // Epilogue: + bias, store.
    float bfr[16];
#pragma unroll
    for (int g = 0; g < 4; ++g) {
        float4 bb = *(const float4*)(bias + d * NG4 + ct * 256 + g * 64 + tx * 4);
        bfr[g * 4 + 0] = bb.x; bfr[g * 4 + 1] = bb.y; bfr[g * 4 + 2] = bb.z; bfr[g * 4 + 3] = bb.w;
    }
#pragma unroll
    for (int i = 0; i < 8; ++i) {
        const int s = ty * 8 + i;
        float* zp = zin + (((size_t)(d * NB + b) * CHUNK + s)) * NG4 + ct * 256;
#pragma unroll
        for (int g = 0; g < 4; ++g) {
            float4 o;
            o.x = acc[i][g * 4 + 0] + bfr[g * 4 + 0];
            o.y = acc[i][g * 4 + 1] + bfr[g * 4 + 1];
            o.z = acc[i][g * 4 + 2] + bfr[g * 4 + 2];
            o.w = acc[i][g * 4 + 3] + bfr[g * 4 + 3];
            *(float4*)(zp + g * 64 + tx * 4) = o;
        }
    }
}

// ---------------------------------------------------------------------------
// Recurrent kernel: one block per (d,b). Whh rows in VGPRs, h broadcast via LDS.
// thread (q in 0..1, j in 0..511): 64 weights of row j.
// ---------------------------------------------------------------------------
__global__ __launch_bounds__(1024) void lstm_rec_kernel(
    const float* __restrict__ Whh,     // [2][512][128]
    const float* __restrict__ zin,     // [2][B][CHUNK][512]
    float*       __restrict__ hout,    // [B][T][256]; we write slice [d*128 .. d*128+128)
    float*       __restrict__ state_h, // [2][B][128]
    float*       __restrict__ state_c, // [2][B][128]
    int c)
{
    __shared__ __align__(16) float h_lds[128];
    __shared__ float p_lds[1024];

    const int bid = blockIdx.x;  // d*128 + b
    const int d = bid >> 7, b = bid & 127;
    const int tid = threadIdx.x;
    const int j = tid & 511, q = tid >> 9;

    float w[64];
    const float* wrow = Whh + ((size_t)(d * NG4 + j)) * NH + q * 64;
#pragma unroll
    for (int kk = 0; kk < 64; kk += 4) {
        float4 t4 = *(const float4*)(wrow + kk);
        w[kk] = t4.x; w[kk + 1] = t4.y; w[kk + 2] = t4.z; w[kk + 3] = t4.w;
    }

    float c_reg = 0.0f;
    if (tid < 128) {
        float h0 = 0.0f;
        if (c != 0) {
            h0    = state_h[(d * NB + b) * NH + tid];
            c_reg = state_c[(d * NB + b) * NH + tid];
        }
        h_lds[tid] = h0;
    }
    __syncthreads();

    const float* zb = zin + ((size_t)(d * NB + b)) * CHUNK * NG4;

    for (int s = 0; s < CHUNK; ++s) {
        // gate threads prefetch this step's zin early (latency hides under FMA)
        float z0 = 0.f, z1 = 0.f, z2 = 0.f, z3 = 0.f;
        if (tid < 128) {
            const float* zr = zb + (size_t)s * NG4;
            z0 = zr[tid]; z1 = zr[128 + tid]; z2 = zr[256 + tid]; z3 = zr[384 + tid];
        }
        float acc = 0.0f;
        const float* hp = h_lds + q * 64;
#pragma unroll
        for (int kk = 0; kk < 64; kk += 4) {
            float4 hv = *(const float4*)(hp + kk);
            acc += w[kk] * hv.x + w[kk + 1] * hv.y + w[kk + 2] * hv.z + w[kk + 3] * hv.w;
        }
        p_lds[tid] = acc;
        __syncthreads();

        if (tid < 128) {
            const float zi = z0 + p_lds[tid]       + p_lds[512 + tid];
            const float zf = z1 + p_lds[128 + tid] + p_lds[640 + tid];
            const float zg = z2 + p_lds[256 + tid] + p_lds[768 + tid];
            const float zo = z3 + p_lds[384 + tid] + p_lds[896 + tid];
            const float ig = sigf(zi), fg = sigf(zf), og = sigf(zo);
            c_reg = fg * c_reg + ig * tanhf(zg);
            const float hn = og * tanhf(c_reg);
            const int ttl = c * CHUNK + s;
            const int t   = d ? (NT - 1 - ttl) : ttl;
            h_lds[tid] = hn;
            hout[((size_t)(b * NT + t)) * 256 + d * NH + tid] = hn;
        }
        __syncthreads();
    }

    if (tid < 128) {
        state_h[(d * NB + b) * NH + tid] = h_lds[tid];
        state_c[(d * NB + b) * NH + tid] = c_reg;
    }
}

// ---------------------------------------------------------------------------
// Emissions: em[b][t][k] = b_out[k] + sum_c h2[b][t][c] * W_out[k][c]
// 1024 blocks x 256 threads; each block does 64 rows (8 iters of 8 rows).
// W_out staged transposed [c][k] in LDS (conflict-free reads).
// ---------------------------------------------------------------------------
__global__ __launch_bounds__(256) void emis_kernel(
    const float* __restrict__ h2,    // [B][T][256]
    const float* __restrict__ Wout,  // [32][256]
    const float* __restrict__ bout,  // [32]
    float*       __restrict__ em)    // [B][T][32]
{
    __shared__ float wt[256 * 32];               // transposed [c][k]
    __shared__ __align__(16) float hrow[8][256];

    const int tid = threadIdx.x;
    const int k = tid & 31;
    const int rl = tid >> 5;  // 0..7

    for (int e = tid; e < 8192; e += 256) {
        const int kk = e >> 8, cc = e & 255;
        wt[cc * 32 + kk] = Wout[e];
    }
    const float bk = bout[k];
    __syncthreads();

    const size_t base = (size_t)blockIdx.x * 64;
    for (int rr = 0; rr < 8; ++rr) {
        const size_t r0 = base + rr * 8;
        for (int e = tid; e < 512; e += 256) {  // 2048 floats as float4
            ((float4*)&hrow[0][0])[e] = ((const float4*)(h2 + r0 * 256))[e];
        }
        __syncthreads();
        float acc = bk;
#pragma unroll 8
        for (int cc = 0; cc < 256; cc += 4) {
            float4 hv = *(const float4*)&hrow[rl][cc];
            acc += hv.x * wt[cc * 32 + k] + hv.y * wt[(cc + 1) * 32 + k] +
                   hv.z * wt[(cc + 2) * 32 + k] + hv.w * wt[(cc + 3) * 32 + k];
        }
        em[(r0 + rl) * NKT + k] = acc;
        __syncthreads();
    }
}

// ---------------------------------------------------------------------------
// Viterbi: one block (1 wave) per batch row. hist kept in LDS; backtrack in-LDS.
// Replicates np add order ((score+trans)+em) and first-index argmax ties.
// lane = j + 32*h ; half h reduces over i in [h*16, h*16+16)
// ---------------------------------------------------------------------------
__global__ __launch_bounds__(64) void viterbi_kernel(
    const float* __restrict__ em,      // [B][T][32]
    const float* __restrict__ start_t, // [32]
    const float* __restrict__ end_t,   // [32]
    const float* __restrict__ trans,   // [32][32]
    int*         __restrict__ out)     // [B][T]
{
    __shared__ float score[32];
    __shared__ float tr[1024];
    __shared__ float fsc[32];
    __shared__ unsigned char hist[(NT - 1) * 32];

    const int b = blockIdx.x;
    const int lane = threadIdx.x;
    const int j = lane & 31, h = lane >> 5;

    for (int e = lane; e < 1024; e += 64) tr[e] = trans[e];
    const float* emb_ = em + (size_t)b * NT * NKT;
    if (lane < 32) score[j] = start_t[j] + emb_[j];
    __syncthreads();

    float em_next = emb_[NKT + j];  // t = 1
    for (int t = 1; t < NT; ++t) {
        const float em_j = em_next;
        if (t + 1 < NT) em_next = emb_[(size_t)(t + 1) * NKT + j];
        float best = -1e30f;
        int bi = 0;
#pragma unroll
        for (int ii = 0; ii < 16; ++ii) {
            const int i = h * 16 + ii;
            const float v = (score[i] + tr[i * 32 + j]) + em_j;  // np add order
            if (v > best) { best = v; bi = i; }                  // strict >: first index wins
        }
        const float ob  = __shfl(best, lane ^ 32);
        const int   obi = __shfl(bi,   lane ^ 32);
        __syncthreads();
        if (h == 0) {
            float ns; int arg;
            if (ob > best) { ns = ob; arg = obi; }  // tie -> low half (smaller i)
            else           { ns = best; arg = bi; }
            score[j] = ns;
            hist[(t - 1) * 32 + j] = (unsigned char)arg;
        }
        __syncthreads();
    }

    if (lane < 32) fsc[j] = score[j] + end_t[j];
    __syncthreads();
    if (lane == 0) {
        float best = -1e30f; int bi = 0;
        for (int i = 0; i < 32; ++i) {
            const float v = fsc[i];
            if (v > best) { best = v; bi = i; }
        }
        int tag = bi;
        out[b * NT + (NT - 1)] = tag;
        for (int t = NT - 2; t >= 0; --t) {
            tag = hist[t * 32 + tag];
            out[b * NT + t] = tag;
        }
    }
}

// ---------------------------------------------------------------------------
extern "C" void kernel_launch(void* const* d_in, const int* in_sizes, int n_in,
                              void* d_out, int out_size, void* d_ws, size_t ws_size,
                              hipStream_t stream) {
    const int*   inputs  = (const int*)d_in[0];
    // d_in[1] = tags (unused by forward/decode)
    const float* emb     = (const float*)d_in[2];
    const float* w_ih_l0 = (const float*)d_in[3];
    const float* w_hh_l0 = (const float*)d_in[4];
    const float* b_l0    = (const float*)d_in[5];
    const float* w_ih_l1 = (const float*)d_in[6];
    const float* w_hh_l1 = (const float*)d_in[7];
    const float* b_l1    = (const float*)d_in[8];
    const float* W_out   = (const float*)d_in[9];
    const float* b_out   = (const float*)d_in[10];
    const float* start_t = (const float*)d_in[11];
    const float* end_t   = (const float*)d_in[12];
    const float* trans   = (const float*)d_in[13];
    int* out = (int*)d_out;

    float* ws  = (float*)d_ws;
    float* zin = ws;                                        // 2*B*CHUNK*512 = 16,777,216
    float* h1  = zin + (size_t)2 * NB * CHUNK * NG4;        // B*T*256       = 16,777,216
    float* h2  = h1 + (size_t)NB * NT * 256;                //               = 16,777,216
    float* sth = h2 + (size_t)NB * NT * 256;                // 2*B*128
    float* stc = sth + (size_t)2 * NB * NH;                 // 2*B*128
    float* em  = stc + (size_t)2 * NB * NH;                 // B*T*32        = 2,097,152

    // Layer 0: chunked input-projection GEMM + recurrence
    for (int c = 0; c < NCH; ++c) {
        proj_gemm<128><<<512, 256, 0, stream>>>(w_ih_l0, b_l0, emb, inputs, zin, c);
        lstm_rec_kernel<<<256, 1024, 0, stream>>>(w_hh_l0, zin, h1, sth, stc, c);
    }
    // Layer 1
    for (int c = 0; c < NCH; ++c) {
        proj_gemm<256><<<512, 256, 0, stream>>>(w_ih_l1, b_l1, h1, nullptr, zin, c);
        lstm_rec_kernel<<<256, 1024, 0, stream>>>(w_hh_l1, zin, h2, sth, stc, c);
    }
    // Emissions + Viterbi decode
    emis_kernel<<<(NB * NT) / 64, 256, 0, stream>>>(h2, W_out, b_out, em);
    viterbi_kernel<<<NB, 64, 0, stream>>>(em, start_t, end_t, trans, out);
}